// Round 5
// baseline (209.820 us; speedup 1.0000x reference)
//
#include <hip/hip_runtime.h>
#include <hip/hip_bf16.h>
#include <hip/hip_fp16.h>

// GCN 2-layer: out = Ahat * relu(Ahat*(X W1)+b1) * W2 + b2
// Round 18: slice-phased aggregation for L2-resident gathers.
//  - src-space split into NS=4 slices of 32768 nodes (xs1 slice 3.2MB,
//    xs2 slice 2.1MB -> fits 4MB XCD L2). Each row's CSR list is grouped
//    by src slice, each (row,slice) sub-list 8-padded (pad -> zero row n;
//    pad gathers hit one hot line, ~free). agg kernels loop slices in
//    order; co-resident blocks concentrate gathers in one slice -> L2 hits.
//  - rp4/re4 int4 per row: per-slice sub-list [start,end).
//  - bucket_csr: 2048-bin (512 rows x 4 slices) hist + scan + scatter.
//  - build place/init, gemm64/gemm32h: R17 verbatim (proven).

#define N_FEAT_IN 64
#define B2SHIFT 9        // 512 dst nodes per coarse bucket
#define CHUNK 4096       // edges per block in place
#define CAP 12288        // bedges bucket region capacity (mean 8163 + 45 sigma)
#define CSRCAP 26624     // csr bucket capacity: CAP + 512*4*7 pad (8-aligned)
#define SSHIFT 15        // src slice = src >> 15 (4 slices for n <= 131072)

struct alignas(8) half4 { __half2 lo, hi; };
struct alignas(16) half8 { __half2 h[4]; };

// ---- init: zero the global bucket cursors ----
__global__ __launch_bounds__(256) void init_k(int* __restrict__ gcur) {
    gcur[threadIdx.x] = 0;
}

// ---- place: per-chunk LDS hist -> global atomic base -> scatter ----
__global__ __launch_bounds__(1024) void place_k(const int* __restrict__ src,
                                                const int* __restrict__ dst,
                                                int* __restrict__ gcur,
                                                unsigned* __restrict__ bedges, int E) {
    __shared__ int h[256];
    __shared__ int cur[256];
    int t = threadIdx.x;
    if (t < 256) h[t] = 0;
    __syncthreads();
    int base = blockIdx.x * CHUNK;
    int end = min(base + CHUNK, E);
    for (int i = base + t; i < end; i += 1024)
        atomicAdd(&h[dst[i] >> B2SHIFT], 1);
    __syncthreads();
    if (t < 256) {
        int cnt = h[t];
        int b0 = cnt ? atomicAdd(&gcur[t], cnt) : 0;  // device-scope
        cur[t] = t * CAP + b0;
    }
    __syncthreads();
    for (int i = base + t; i < end; i += 1024) {
        int d = dst[i];
        int p = atomicAdd(&cur[d >> B2SHIFT], 1);     // LDS atomic
        bedges[p] = ((unsigned)src[i] << B2SHIFT) | (unsigned)(d & 511);
    }
}

// ---- bucket_csr: (row,slice) hist -> padded scan -> rp4/re4/dinv -> scatter ----
__global__ __launch_bounds__(1024) void bucket_csr(const int* __restrict__ gcnt,
                                                   const unsigned* __restrict__ bedges,
                                                   int4* __restrict__ rp4,
                                                   int4* __restrict__ re4,
                                                   float* __restrict__ dinv,
                                                   int* __restrict__ csr_src, int n) {
    __shared__ int lh[2048];
    __shared__ int cur[2048];
    int t = threadIdx.x;
    lh[t] = 0; lh[t + 1024] = 0;
    __syncthreads();
    int b = blockIdx.x;
    int beg = b * CAP;
    int end = beg + gcnt[b];
    for (int i = beg + t; i < end; i += 1024) {
        unsigned v = bedges[i];
        atomicAdd(&lh[(v & 511) * 4 + (v >> (B2SHIFT + SSHIFT))], 1);
    }
    __syncthreads();
    int raw[4], pad[4];
    if (t < 512) {
#pragma unroll
        for (int s = 0; s < 4; ++s) {
            raw[s] = lh[t * 4 + s];
            pad[s] = (raw[s] + 7) & ~7;
        }
    }
    __syncthreads();
    if (t < 512) {
#pragma unroll
        for (int s = 0; s < 4; ++s) lh[t * 4 + s] = pad[s];
    }
    __syncthreads();
    // inclusive Hillis-Steele scan over 2048 bins (2 elems/thread)
    for (int off = 1; off < 2048; off <<= 1) {
        int a0 = (t >= off) ? lh[t - off] : 0;
        int a1 = (t + 1024 >= off) ? lh[t + 1024 - off] : 0;
        __syncthreads();
        lh[t] += a0;
        lh[t + 1024] += a1;
        __syncthreads();
    }
    int pb = b * CSRCAP;
    if (t < 512) {
        int d = (b << B2SHIFT) + t;
        int e[4];
#pragma unroll
        for (int s = 0; s < 4; ++s) e[s] = lh[t * 4 + s] - pad[s];  // excl start
#pragma unroll
        for (int s = 0; s < 4; ++s) cur[t * 4 + s] = pb + e[s];
        if (d < n) {
            int4 rp = make_int4(pb + e[0], pb + e[1], pb + e[2], pb + e[3]);
            int4 re = make_int4(pb + e[0] + pad[0], pb + e[1] + pad[1],
                                pb + e[2] + pad[2], pb + e[3] + pad[3]);
            rp4[d] = rp;
            re4[d] = re;
            int c = raw[0] + raw[1] + raw[2] + raw[3];
            dinv[d] = rsqrtf((float)c + 1.0f);
#pragma unroll
            for (int s = 0; s < 4; ++s)
                for (int i = raw[s]; i < pad[s]; ++i)
                    csr_src[pb + e[s] + i] = n;       // pad -> zero row
        }
    }
    __syncthreads();
    for (int i = beg + t; i < end; i += 1024) {
        unsigned v = bedges[i];
        int p = atomicAdd(&cur[(v & 511) * 4 + (v >> (B2SHIFT + SSHIFT))], 1);
        csr_src[p] = (int)(v >> B2SHIFT);
    }
}

// ---- gemm64: xs1[n+1][64] fp16 = half( dinv[row] * (X W1) ) ----
__global__ __launch_bounds__(256) void gemm64(const float* __restrict__ A,
                                              const float* __restrict__ W,
                                              const float* __restrict__ dinv,
                                              __half* __restrict__ outh, int n) {
    __shared__ float AsT[64][132];   // [k][row]
    __shared__ float Ws[64][64];

    const int t = threadIdx.x;
    const int r0 = blockIdx.x * 128;

    if (blockIdx.x == 0 && t < 64)   // zero pad row n
        outh[(size_t)n * 64 + t] = __float2half(0.f);

    for (int i = t; i < 64 * 16; i += 256) {
        int k = i >> 4;
        int c4 = (i & 15) * 4;
        *(float4*)&Ws[k][c4] = *(const float4*)&W[k * 64 + c4];
    }
    for (int i = t; i < 128 * 16; i += 256) {
        int row = i >> 4;
        int c4 = (i & 15) * 4;
        int g = r0 + row;
        float4 v = make_float4(0.f, 0.f, 0.f, 0.f);
        if (g < n) v = *(const float4*)&A[(size_t)g * 64 + c4];
        AsT[c4 + 0][row] = v.x;
        AsT[c4 + 1][row] = v.y;
        AsT[c4 + 2][row] = v.z;
        AsT[c4 + 3][row] = v.w;
    }
    __syncthreads();

    const int rg = t >> 3;
    const int cg = t & 7;
    float acc[4][8];
#pragma unroll
    for (int r = 0; r < 4; ++r)
#pragma unroll
        for (int j = 0; j < 8; ++j) acc[r][j] = 0.f;

#pragma unroll 4
    for (int k = 0; k < 64; ++k) {
        float4 a = *(const float4*)&AsT[k][rg * 4];
        float4 w0 = *(const float4*)&Ws[k][cg * 8];
        float4 w1 = *(const float4*)&Ws[k][cg * 8 + 4];
        float av[4] = {a.x, a.y, a.z, a.w};
        float wv[8] = {w0.x, w0.y, w0.z, w0.w, w1.x, w1.y, w1.z, w1.w};
#pragma unroll
        for (int r = 0; r < 4; ++r)
#pragma unroll
            for (int j = 0; j < 8; ++j)
                acc[r][j] = fmaf(av[r], wv[j], acc[r][j]);
    }

#pragma unroll
    for (int r = 0; r < 4; ++r) {
        int g = r0 + rg * 4 + r;
        if (g < n) {
            float sc = dinv[g];
            half8 h;
            h.h[0] = __floats2half2_rn(acc[r][0] * sc, acc[r][1] * sc);
            h.h[1] = __floats2half2_rn(acc[r][2] * sc, acc[r][3] * sc);
            h.h[2] = __floats2half2_rn(acc[r][4] * sc, acc[r][5] * sc);
            h.h[3] = __floats2half2_rn(acc[r][6] * sc, acc[r][7] * sc);
            *(half8*)&outh[(size_t)g * 64 + cg * 8] = h;
        }
    }
}

#define ACC8(v)                                                       \
    {                                                                 \
        float2 f0 = __half22float2((v).h[0]);                         \
        float2 f1 = __half22float2((v).h[1]);                         \
        float2 f2 = __half22float2((v).h[2]);                         \
        float2 f3 = __half22float2((v).h[3]);                         \
        a0 += f0.x; a1 += f0.y; a2 += f1.x; a3 += f1.y;               \
        a4 += f2.x; a5 += f2.y; a6 += f3.x; a7 += f3.y;               \
    }

#define AGG_SLICE_LOOP(STRIDE)                                        \
    for (int s = 0; s < 4; ++s) {                                     \
        int beg = rps[s];                                             \
        int end = res[s];                                             \
        if (beg >= end) continue;                                     \
        int4 ia = *(const int4*)&csr_src[beg];                        \
        int4 ib = *(const int4*)&csr_src[beg + 4];                    \
        int jb = beg;                                                 \
        for (;;) {                                                    \
            int jn = jb + 8;                                          \
            bool more = jn < end;                                     \
            int js = more ? jn : beg;                                 \
            int4 na = *(const int4*)&csr_src[js];                     \
            int4 nb = *(const int4*)&csr_src[js + 4];                 \
            half8 v0 = xrow[(size_t)ia.x * STRIDE];                   \
            half8 v1 = xrow[(size_t)ia.y * STRIDE];                   \
            half8 v2 = xrow[(size_t)ia.z * STRIDE];                   \
            half8 v3 = xrow[(size_t)ia.w * STRIDE];                   \
            half8 v4 = xrow[(size_t)ib.x * STRIDE];                   \
            half8 v5 = xrow[(size_t)ib.y * STRIDE];                   \
            half8 v6 = xrow[(size_t)ib.z * STRIDE];                   \
            half8 v7 = xrow[(size_t)ib.w * STRIDE];                   \
            ACC8(v0); ACC8(v1); ACC8(v2); ACC8(v3);                   \
            ACC8(v4); ACC8(v5); ACC8(v6); ACC8(v7);                   \
            if (!more) break;                                         \
            jb = jn; ia = na; ib = nb;                                \
        }                                                             \
    }

// ---- agg64: 8 rows/wave, 8 lanes/row, half8/lane; slice-phased gathers ----
__global__ __launch_bounds__(256) void agg64(const int4* __restrict__ rp4,
                                             const int4* __restrict__ re4,
                                             const int* __restrict__ csr_src,
                                             const float* __restrict__ dinv,
                                             const __half* __restrict__ xs1,
                                             const float* __restrict__ b1,
                                             __half* __restrict__ th, int n) {
    int d = blockIdx.x * 32 + (threadIdx.x >> 3);  // 32 rows/block
    if (d >= n) return;
    int c = threadIdx.x & 7;                       // half8 slice (feats 8c..8c+7)
    const half8* __restrict__ xrow = (const half8*)xs1 + c;  // row stride 8 half8

    half8 sv = xrow[(size_t)d * 8];                // self-loop
    float a0, a1, a2, a3, a4, a5, a6, a7;
    {
        float2 f0 = __half22float2(sv.h[0]), f1 = __half22float2(sv.h[1]);
        float2 f2 = __half22float2(sv.h[2]), f3 = __half22float2(sv.h[3]);
        a0 = f0.x; a1 = f0.y; a2 = f1.x; a3 = f1.y;
        a4 = f2.x; a5 = f2.y; a6 = f3.x; a7 = f3.y;
    }

    int4 rp = rp4[d];
    int4 re = re4[d];
    int rps[4] = {rp.x, rp.y, rp.z, rp.w};
    int res[4] = {re.x, re.y, re.z, re.w};
    AGG_SLICE_LOOP(8)

    float di = dinv[d];
    float4 ba = *(const float4*)&b1[8 * c];
    float4 bb = *(const float4*)&b1[8 * c + 4];
    float t0 = fmaxf(fmaf(di, a0, ba.x), 0.f);
    float t1 = fmaxf(fmaf(di, a1, ba.y), 0.f);
    float t2 = fmaxf(fmaf(di, a2, ba.z), 0.f);
    float t3 = fmaxf(fmaf(di, a3, ba.w), 0.f);
    float t4 = fmaxf(fmaf(di, a4, bb.x), 0.f);
    float t5 = fmaxf(fmaf(di, a5, bb.y), 0.f);
    float t6 = fmaxf(fmaf(di, a6, bb.z), 0.f);
    float t7 = fmaxf(fmaf(di, a7, bb.w), 0.f);
    half8 o;
    o.h[0] = __floats2half2_rn(t0, t1);
    o.h[1] = __floats2half2_rn(t2, t3);
    o.h[2] = __floats2half2_rn(t4, t5);
    o.h[3] = __floats2half2_rn(t6, t7);
    *(half8*)&th[(size_t)d * 64 + 8 * c] = o;
}

// ---- gemm32h: xs2[n+1][32] fp16 = half( dinv[row] * (t W2) ) ----
__global__ __launch_bounds__(256) void gemm32h(const __half* __restrict__ Ah,
                                               const float* __restrict__ W,
                                               const float* __restrict__ dinv,
                                               __half* __restrict__ outh, int n) {
    __shared__ float AsT[64][260];
    __shared__ float Ws[64][32];

    const int t = threadIdx.x;
    const int r0 = blockIdx.x * 256;

    if (blockIdx.x == 0 && t < 32)   // zero pad row n
        outh[(size_t)n * 32 + t] = __float2half(0.f);

    for (int i = t; i < 64 * 8; i += 256) {
        int k = i >> 3;
        int c4 = (i & 7) * 4;
        *(float4*)&Ws[k][c4] = *(const float4*)&W[k * 32 + c4];
    }
    for (int i = t; i < 256 * 8; i += 256) {
        int row = i >> 3;
        int c8 = (i & 7) * 8;
        int g = r0 + row;
        if (g < n) {
            half8 hv = *(const half8*)&Ah[(size_t)g * 64 + c8];
            float2 f0 = __half22float2(hv.h[0]), f1 = __half22float2(hv.h[1]);
            float2 f2 = __half22float2(hv.h[2]), f3 = __half22float2(hv.h[3]);
            AsT[c8 + 0][row] = f0.x; AsT[c8 + 1][row] = f0.y;
            AsT[c8 + 2][row] = f1.x; AsT[c8 + 3][row] = f1.y;
            AsT[c8 + 4][row] = f2.x; AsT[c8 + 5][row] = f2.y;
            AsT[c8 + 6][row] = f3.x; AsT[c8 + 7][row] = f3.y;
        } else {
#pragma unroll
            for (int j = 0; j < 8; ++j) AsT[c8 + j][row] = 0.f;
        }
    }
    __syncthreads();

    const int rg = t >> 2;
    const int cg = t & 3;
    float acc[4][8];
#pragma unroll
    for (int r = 0; r < 4; ++r)
#pragma unroll
        for (int j = 0; j < 8; ++j) acc[r][j] = 0.f;

#pragma unroll 4
    for (int k = 0; k < 64; ++k) {
        float4 a = *(const float4*)&AsT[k][rg * 4];
        float4 w0 = *(const float4*)&Ws[k][cg * 8];
        float4 w1 = *(const float4*)&Ws[k][cg * 8 + 4];
        float av[4] = {a.x, a.y, a.z, a.w};
        float wv[8] = {w0.x, w0.y, w0.z, w0.w, w1.x, w1.y, w1.z, w1.w};
#pragma unroll
        for (int r = 0; r < 4; ++r)
#pragma unroll
            for (int j = 0; j < 8; ++j)
                acc[r][j] = fmaf(av[r], wv[j], acc[r][j]);
    }

#pragma unroll
    for (int r = 0; r < 4; ++r) {
        int g = r0 + rg * 4 + r;
        if (g < n) {
            float sc = dinv[g];
            half8 h;
            h.h[0] = __floats2half2_rn(acc[r][0] * sc, acc[r][1] * sc);
            h.h[1] = __floats2half2_rn(acc[r][2] * sc, acc[r][3] * sc);
            h.h[2] = __floats2half2_rn(acc[r][4] * sc, acc[r][5] * sc);
            h.h[3] = __floats2half2_rn(acc[r][6] * sc, acc[r][7] * sc);
            *(half8*)&outh[(size_t)g * 32 + cg * 8] = h;
        }
    }
}

// ---- agg32: 16 rows/wave, 4 lanes/row, half8/lane; slice-phased gathers ----
__global__ __launch_bounds__(256) void agg32(const int4* __restrict__ rp4,
                                             const int4* __restrict__ re4,
                                             const int* __restrict__ csr_src,
                                             const float* __restrict__ dinv,
                                             const __half* __restrict__ xs2,
                                             const float* __restrict__ b2,
                                             float* __restrict__ out, int n) {
    int d = blockIdx.x * 64 + (threadIdx.x >> 2);  // 64 rows/block
    if (d >= n) return;
    int c = threadIdx.x & 3;                       // half8 slice (feats 8c..8c+7)
    const half8* __restrict__ xrow = (const half8*)xs2 + c;  // row stride 4 half8

    half8 sv = xrow[(size_t)d * 4];                // self-loop
    float a0, a1, a2, a3, a4, a5, a6, a7;
    {
        float2 f0 = __half22float2(sv.h[0]), f1 = __half22float2(sv.h[1]);
        float2 f2 = __half22float2(sv.h[2]), f3 = __half22float2(sv.h[3]);
        a0 = f0.x; a1 = f0.y; a2 = f1.x; a3 = f1.y;
        a4 = f2.x; a5 = f2.y; a6 = f3.x; a7 = f3.y;
    }

    int4 rp = rp4[d];
    int4 re = re4[d];
    int rps[4] = {rp.x, rp.y, rp.z, rp.w};
    int res[4] = {re.x, re.y, re.z, re.w};
    AGG_SLICE_LOOP(4)

    float di = dinv[d];
    float4 ba = *(const float4*)&b2[8 * c];
    float4 bb = *(const float4*)&b2[8 * c + 4];
    float4 r0, r1;
    r0.x = fmaf(di, a0, ba.x);
    r0.y = fmaf(di, a1, ba.y);
    r0.z = fmaf(di, a2, ba.z);
    r0.w = fmaf(di, a3, ba.w);
    r1.x = fmaf(di, a4, bb.x);
    r1.y = fmaf(di, a5, bb.y);
    r1.z = fmaf(di, a6, bb.z);
    r1.w = fmaf(di, a7, bb.w);
    *(float4*)&out[(size_t)d * 32 + 8 * c] = r0;
    *(float4*)&out[(size_t)d * 32 + 8 * c + 4] = r1;
}

extern "C" void kernel_launch(void* const* d_in, const int* in_sizes, int n_in,
                              void* d_out, int out_size, void* d_ws, size_t ws_size,
                              hipStream_t stream) {
    const float* x  = (const float*)d_in[0];   // [n, 64]
    const int*   ei = (const int*)d_in[1];     // [2, E]
    const float* W1 = (const float*)d_in[2];   // [64, 64]
    const float* b1 = (const float*)d_in[3];   // [64]
    const float* W2 = (const float*)d_in[4];   // [64, 32]
    const float* b2 = (const float*)d_in[5];   // [32]
    float* out = (float*)d_out;                // [n, 32]

    const int n = in_sizes[0] / N_FEAT_IN;     // 100000
    const int E = in_sizes[1] / 2;             // 1600000
    const int* srcI = ei;
    const int* dstI = ei + E;

    const int NB = (n + 511) >> B2SHIFT;       // 196 coarse buckets
    const int NR = (E + CHUNK - 1) / CHUNK;    // 391 chunks

    // workspace layout (256B aligned)
    char* ws = (char*)d_ws;
    size_t off = 0;
    auto alloc = [&](size_t bytes) {
        void* p = ws + off;
        off += (bytes + 255) & ~(size_t)255;
        return p;
    };
    float*    dinv    = (float*)alloc((size_t)n * 4);
    int4*     rp4     = (int4*)alloc((size_t)n * 16);
    int4*     re4     = (int4*)alloc((size_t)n * 16);
    int*      gcur    = (int*)alloc((size_t)256 * 4);
    unsigned* bedges  = (unsigned*)alloc((size_t)NB * CAP * 4);     // 9.6MB
    int*      csr_src = (int*)alloc((size_t)NB * CSRCAP * 4);       // 20.9MB
    __half*   xs1     = (__half*)alloc((size_t)(n + 1) * 64 * 2);   // +pad row
    __half*   th      = (__half*)alloc((size_t)n * 64 * 2);
    __half*   xs2     = (__half*)alloc((size_t)(n + 1) * 32 * 2);   // +pad row

    // 1) build: init cursors -> place into CAP-strided buckets -> sliced CSR
    init_k<<<1, 256, 0, stream>>>(gcur);
    place_k<<<NR, 1024, 0, stream>>>(srcI, dstI, gcur, bedges, E);
    bucket_csr<<<NB, 1024, 0, stream>>>(gcur, bedges, rp4, re4, dinv, csr_src, n);

    // 2) layer 1 GEMM: xs1 = half(dinv .* (X W1))
    gemm64<<<(n + 127) / 128, 256, 0, stream>>>(x, W1, dinv, xs1, n);

    // 3) layer-1 aggregate: t = relu(dinv*(gather+self) + b1)
    agg64<<<(n + 31) / 32, 256, 0, stream>>>(rp4, re4, csr_src, dinv, xs1, b1, th, n);

    // 4) layer-2 transform: xs2 = half(dinv .* (t W2))
    gemm32h<<<(n + 255) / 256, 256, 0, stream>>>(th, W2, dinv, xs2, n);

    // 5) layer-2 aggregate -> out
    agg32<<<(n + 63) / 64, 256, 0, stream>>>(rp4, re4, csr_src, dinv, xs2, b2, out, n);
}

// Round 6
// 201.091 us; speedup vs baseline: 1.0434x; 1.0434x over previous
//
#include <hip/hip_runtime.h>
#include <hip/hip_bf16.h>
#include <hip/hip_fp16.h>

// GCN 2-layer: out = Ahat * relu(Ahat*(X W1)+b1) * W2 + b2
// Round 19: R17 base + MLP-doubled aggregation (16 gathers in flight/thread).
//  - CSR rows padded to multiples of 16 (pad -> zero row n, adds +0.0 exact).
//  - agg64/agg32: per iteration load 4x int4 indices, issue 16 half8 gathers
//    straight-line, then 16 ACCs in sequential edge order (bitwise-identical
//    row sums vs 8-batch). __launch_bounds__(256,4) caps VGPR at 128 so
//    occupancy holds 4 waves/SIMD -> per-SIMD outstanding gathers 32 -> 64.
//  - build: R17 atomic-base 3-dispatch pipeline, pad16 in bucket_csr.
//  - gemms: R17 register-tiled (proven).

#define N_FEAT_IN 64
#define B2SHIFT 9        // 512 dst nodes per coarse bucket
#define CHUNK 4096       // edges per block in place
#define CAP 12288        // bedges bucket region capacity (mean 8163 + 45 sigma)
#define CSRCAP 20480     // csr bucket capacity: CAP + 512*15 pad (16-aligned)

struct alignas(8) half4 { __half2 lo, hi; };
struct alignas(16) half8 { __half2 h[4]; };

// ---- init: zero the global bucket cursors ----
__global__ __launch_bounds__(256) void init_k(int* __restrict__ gcur) {
    gcur[threadIdx.x] = 0;
}

// ---- place: per-chunk LDS hist -> global atomic base -> scatter ----
__global__ __launch_bounds__(1024) void place_k(const int* __restrict__ src,
                                                const int* __restrict__ dst,
                                                int* __restrict__ gcur,
                                                unsigned* __restrict__ bedges, int E) {
    __shared__ int h[256];
    __shared__ int cur[256];
    int t = threadIdx.x;
    if (t < 256) h[t] = 0;
    __syncthreads();
    int base = blockIdx.x * CHUNK;
    int end = min(base + CHUNK, E);
    for (int i = base + t; i < end; i += 1024)
        atomicAdd(&h[dst[i] >> B2SHIFT], 1);
    __syncthreads();
    if (t < 256) {
        int cnt = h[t];
        int b0 = cnt ? atomicAdd(&gcur[t], cnt) : 0;  // device-scope
        cur[t] = t * CAP + b0;
    }
    __syncthreads();
    for (int i = base + t; i < end; i += 1024) {
        int d = dst[i];
        int p = atomicAdd(&cur[d >> B2SHIFT], 1);     // LDS atomic
        bedges[p] = ((unsigned)src[i] << B2SHIFT) | (unsigned)(d & 511);
    }
}

// ---- bucket_csr: hist -> pad16 scan -> row_ptr/rend/dinv -> scatter ----
__global__ __launch_bounds__(1024) void bucket_csr(const int* __restrict__ gcnt,
                                                   const unsigned* __restrict__ bedges,
                                                   int* __restrict__ row_ptr,
                                                   int* __restrict__ rend,
                                                   float* __restrict__ dinv,
                                                   int* __restrict__ csr_src, int n) {
    __shared__ int lh[512];
    __shared__ int cur[512];
    int t = threadIdx.x;
    if (t < 512) lh[t] = 0;
    __syncthreads();
    int b = blockIdx.x;
    int beg = b * CAP;
    int end = beg + gcnt[b];
    for (int i = beg + t; i < end; i += 1024)
        atomicAdd(&lh[bedges[i] & 511], 1);
    __syncthreads();
    int c = (t < 512) ? lh[t] : 0;       // true degree (no self-loop)
    __syncthreads();
    int cp = (c + 15) & ~15;             // padded degree (16-aligned)
    if (t < 512) lh[t] = cp;
    __syncthreads();
    for (int off = 1; off < 512; off <<= 1) {
        int a = (t < 512 && t >= off) ? lh[t - off] : 0;
        __syncthreads();
        if (t < 512) lh[t] += a;
        __syncthreads();
    }
    int pb = b * CSRCAP;                 // 16-aligned bucket csr base
    if (t < 512) {
        int d = (b << B2SHIFT) + t;
        int rbeg = pb + lh[t] - cp;      // 16-aligned exclusive padded offset
        cur[t] = rbeg;
        if (d < n) {
            row_ptr[d] = rbeg;
            rend[d] = rbeg + cp;
            dinv[d] = rsqrtf((float)c + 1.0f);
            for (int i = c; i < cp; ++i) csr_src[rbeg + i] = n;  // pad -> zero row
        }
    }
    __syncthreads();
    for (int i = beg + t; i < end; i += 1024) {
        unsigned v = bedges[i];
        int p = atomicAdd(&cur[v & 511], 1);  // LDS atomic
        csr_src[p] = (int)(v >> B2SHIFT);
    }
}

// ---- gemm64: xs1[n+1][64] fp16 = half( dinv[row] * (X W1) ) ----
__global__ __launch_bounds__(256) void gemm64(const float* __restrict__ A,
                                              const float* __restrict__ W,
                                              const float* __restrict__ dinv,
                                              __half* __restrict__ outh, int n) {
    __shared__ float AsT[64][132];   // [k][row]
    __shared__ float Ws[64][64];

    const int t = threadIdx.x;
    const int r0 = blockIdx.x * 128;

    if (blockIdx.x == 0 && t < 64)   // zero pad row n
        outh[(size_t)n * 64 + t] = __float2half(0.f);

    for (int i = t; i < 64 * 16; i += 256) {
        int k = i >> 4;
        int c4 = (i & 15) * 4;
        *(float4*)&Ws[k][c4] = *(const float4*)&W[k * 64 + c4];
    }
    for (int i = t; i < 128 * 16; i += 256) {
        int row = i >> 4;
        int c4 = (i & 15) * 4;
        int g = r0 + row;
        float4 v = make_float4(0.f, 0.f, 0.f, 0.f);
        if (g < n) v = *(const float4*)&A[(size_t)g * 64 + c4];
        AsT[c4 + 0][row] = v.x;
        AsT[c4 + 1][row] = v.y;
        AsT[c4 + 2][row] = v.z;
        AsT[c4 + 3][row] = v.w;
    }
    __syncthreads();

    const int rg = t >> 3;
    const int cg = t & 7;
    float acc[4][8];
#pragma unroll
    for (int r = 0; r < 4; ++r)
#pragma unroll
        for (int j = 0; j < 8; ++j) acc[r][j] = 0.f;

#pragma unroll 4
    for (int k = 0; k < 64; ++k) {
        float4 a = *(const float4*)&AsT[k][rg * 4];
        float4 w0 = *(const float4*)&Ws[k][cg * 8];
        float4 w1 = *(const float4*)&Ws[k][cg * 8 + 4];
        float av[4] = {a.x, a.y, a.z, a.w};
        float wv[8] = {w0.x, w0.y, w0.z, w0.w, w1.x, w1.y, w1.z, w1.w};
#pragma unroll
        for (int r = 0; r < 4; ++r)
#pragma unroll
            for (int j = 0; j < 8; ++j)
                acc[r][j] = fmaf(av[r], wv[j], acc[r][j]);
    }

#pragma unroll
    for (int r = 0; r < 4; ++r) {
        int g = r0 + rg * 4 + r;
        if (g < n) {
            float sc = dinv[g];
            half8 h;
            h.h[0] = __floats2half2_rn(acc[r][0] * sc, acc[r][1] * sc);
            h.h[1] = __floats2half2_rn(acc[r][2] * sc, acc[r][3] * sc);
            h.h[2] = __floats2half2_rn(acc[r][4] * sc, acc[r][5] * sc);
            h.h[3] = __floats2half2_rn(acc[r][6] * sc, acc[r][7] * sc);
            *(half8*)&outh[(size_t)g * 64 + cg * 8] = h;
        }
    }
}

#define ACC8(v)                                                       \
    {                                                                 \
        float2 f0 = __half22float2((v).h[0]);                         \
        float2 f1 = __half22float2((v).h[1]);                         \
        float2 f2 = __half22float2((v).h[2]);                         \
        float2 f3 = __half22float2((v).h[3]);                         \
        a0 += f0.x; a1 += f0.y; a2 += f1.x; a3 += f1.y;               \
        a4 += f2.x; a5 += f2.y; a6 += f3.x; a7 += f3.y;               \
    }

// 16 gathers in flight, then 16 ACCs in sequential edge order.
#define AGG_LOOP16(STRIDE)                                            \
    if (beg < end) {                                                  \
        int4 ia = *(const int4*)&csr_src[beg];                        \
        int4 ib = *(const int4*)&csr_src[beg + 4];                    \
        int4 ic = *(const int4*)&csr_src[beg + 8];                    \
        int4 id = *(const int4*)&csr_src[beg + 12];                   \
        int jb = beg;                                                 \
        for (;;) {                                                    \
            int jn = jb + 16;                                         \
            bool more = jn < end;                                     \
            int js = more ? jn : beg;                                 \
            int4 na = *(const int4*)&csr_src[js];                     \
            int4 nb = *(const int4*)&csr_src[js + 4];                 \
            int4 nc = *(const int4*)&csr_src[js + 8];                 \
            int4 nd = *(const int4*)&csr_src[js + 12];                \
            half8 v0  = xrow[(size_t)ia.x * STRIDE];                  \
            half8 v1  = xrow[(size_t)ia.y * STRIDE];                  \
            half8 v2  = xrow[(size_t)ia.z * STRIDE];                  \
            half8 v3  = xrow[(size_t)ia.w * STRIDE];                  \
            half8 v4  = xrow[(size_t)ib.x * STRIDE];                  \
            half8 v5  = xrow[(size_t)ib.y * STRIDE];                  \
            half8 v6  = xrow[(size_t)ib.z * STRIDE];                  \
            half8 v7  = xrow[(size_t)ib.w * STRIDE];                  \
            half8 v8  = xrow[(size_t)ic.x * STRIDE];                  \
            half8 v9  = xrow[(size_t)ic.y * STRIDE];                  \
            half8 v10 = xrow[(size_t)ic.z * STRIDE];                  \
            half8 v11 = xrow[(size_t)ic.w * STRIDE];                  \
            half8 v12 = xrow[(size_t)id.x * STRIDE];                  \
            half8 v13 = xrow[(size_t)id.y * STRIDE];                  \
            half8 v14 = xrow[(size_t)id.z * STRIDE];                  \
            half8 v15 = xrow[(size_t)id.w * STRIDE];                  \
            ACC8(v0);  ACC8(v1);  ACC8(v2);  ACC8(v3);                \
            ACC8(v4);  ACC8(v5);  ACC8(v6);  ACC8(v7);                \
            ACC8(v8);  ACC8(v9);  ACC8(v10); ACC8(v11);               \
            ACC8(v12); ACC8(v13); ACC8(v14); ACC8(v15);               \
            if (!more) break;                                         \
            jb = jn; ia = na; ib = nb; ic = nc; id = nd;              \
        }                                                             \
    }

// ---- agg64: 8 rows/wave, 8 lanes/row, half8/lane; t = relu(dinv*acc+b1) ----
__global__ __launch_bounds__(256, 4) void agg64(const int* __restrict__ row_ptr,
                                                const int* __restrict__ rend,
                                                const int* __restrict__ csr_src,
                                                const float* __restrict__ dinv,
                                                const __half* __restrict__ xs1,
                                                const float* __restrict__ b1,
                                                __half* __restrict__ th, int n) {
    int d = blockIdx.x * 32 + (threadIdx.x >> 3);  // 32 rows/block
    if (d >= n) return;
    int c = threadIdx.x & 7;                       // half8 slice (feats 8c..8c+7)
    const half8* __restrict__ xrow = (const half8*)xs1 + c;  // row stride 8 half8

    half8 sv = xrow[(size_t)d * 8];                // self-loop
    float a0, a1, a2, a3, a4, a5, a6, a7;
    {
        float2 f0 = __half22float2(sv.h[0]), f1 = __half22float2(sv.h[1]);
        float2 f2 = __half22float2(sv.h[2]), f3 = __half22float2(sv.h[3]);
        a0 = f0.x; a1 = f0.y; a2 = f1.x; a3 = f1.y;
        a4 = f2.x; a5 = f2.y; a6 = f3.x; a7 = f3.y;
    }

    int beg = row_ptr[d];
    int end = rend[d];
    AGG_LOOP16(8)

    float di = dinv[d];
    float4 ba = *(const float4*)&b1[8 * c];
    float4 bb = *(const float4*)&b1[8 * c + 4];
    float t0 = fmaxf(fmaf(di, a0, ba.x), 0.f);
    float t1 = fmaxf(fmaf(di, a1, ba.y), 0.f);
    float t2 = fmaxf(fmaf(di, a2, ba.z), 0.f);
    float t3 = fmaxf(fmaf(di, a3, ba.w), 0.f);
    float t4 = fmaxf(fmaf(di, a4, bb.x), 0.f);
    float t5 = fmaxf(fmaf(di, a5, bb.y), 0.f);
    float t6 = fmaxf(fmaf(di, a6, bb.z), 0.f);
    float t7 = fmaxf(fmaf(di, a7, bb.w), 0.f);
    half8 o;
    o.h[0] = __floats2half2_rn(t0, t1);
    o.h[1] = __floats2half2_rn(t2, t3);
    o.h[2] = __floats2half2_rn(t4, t5);
    o.h[3] = __floats2half2_rn(t6, t7);
    *(half8*)&th[(size_t)d * 64 + 8 * c] = o;
}

// ---- gemm32h: xs2[n+1][32] fp16 = half( dinv[row] * (t W2) ) ----
__global__ __launch_bounds__(256) void gemm32h(const __half* __restrict__ Ah,
                                               const float* __restrict__ W,
                                               const float* __restrict__ dinv,
                                               __half* __restrict__ outh, int n) {
    __shared__ float AsT[64][260];
    __shared__ float Ws[64][32];

    const int t = threadIdx.x;
    const int r0 = blockIdx.x * 256;

    if (blockIdx.x == 0 && t < 32)   // zero pad row n
        outh[(size_t)n * 32 + t] = __float2half(0.f);

    for (int i = t; i < 64 * 8; i += 256) {
        int k = i >> 3;
        int c4 = (i & 7) * 4;
        *(float4*)&Ws[k][c4] = *(const float4*)&W[k * 32 + c4];
    }
    for (int i = t; i < 256 * 8; i += 256) {
        int row = i >> 3;
        int c8 = (i & 7) * 8;
        int g = r0 + row;
        if (g < n) {
            half8 hv = *(const half8*)&Ah[(size_t)g * 64 + c8];
            float2 f0 = __half22float2(hv.h[0]), f1 = __half22float2(hv.h[1]);
            float2 f2 = __half22float2(hv.h[2]), f3 = __half22float2(hv.h[3]);
            AsT[c8 + 0][row] = f0.x; AsT[c8 + 1][row] = f0.y;
            AsT[c8 + 2][row] = f1.x; AsT[c8 + 3][row] = f1.y;
            AsT[c8 + 4][row] = f2.x; AsT[c8 + 5][row] = f2.y;
            AsT[c8 + 6][row] = f3.x; AsT[c8 + 7][row] = f3.y;
        } else {
#pragma unroll
            for (int j = 0; j < 8; ++j) AsT[c8 + j][row] = 0.f;
        }
    }
    __syncthreads();

    const int rg = t >> 2;
    const int cg = t & 3;
    float acc[4][8];
#pragma unroll
    for (int r = 0; r < 4; ++r)
#pragma unroll
        for (int j = 0; j < 8; ++j) acc[r][j] = 0.f;

#pragma unroll 4
    for (int k = 0; k < 64; ++k) {
        float4 a = *(const float4*)&AsT[k][rg * 4];
        float4 w0 = *(const float4*)&Ws[k][cg * 8];
        float4 w1 = *(const float4*)&Ws[k][cg * 8 + 4];
        float av[4] = {a.x, a.y, a.z, a.w};
        float wv[8] = {w0.x, w0.y, w0.z, w0.w, w1.x, w1.y, w1.z, w1.w};
#pragma unroll
        for (int r = 0; r < 4; ++r)
#pragma unroll
            for (int j = 0; j < 8; ++j)
                acc[r][j] = fmaf(av[r], wv[j], acc[r][j]);
    }

#pragma unroll
    for (int r = 0; r < 4; ++r) {
        int g = r0 + rg * 4 + r;
        if (g < n) {
            float sc = dinv[g];
            half8 h;
            h.h[0] = __floats2half2_rn(acc[r][0] * sc, acc[r][1] * sc);
            h.h[1] = __floats2half2_rn(acc[r][2] * sc, acc[r][3] * sc);
            h.h[2] = __floats2half2_rn(acc[r][4] * sc, acc[r][5] * sc);
            h.h[3] = __floats2half2_rn(acc[r][6] * sc, acc[r][7] * sc);
            *(half8*)&outh[(size_t)g * 32 + cg * 8] = h;
        }
    }
}

// ---- agg32: 16 rows/wave, 4 lanes/row, half8/lane; out = dinv*acc + b2 ----
__global__ __launch_bounds__(256, 4) void agg32(const int* __restrict__ row_ptr,
                                                const int* __restrict__ rend,
                                                const int* __restrict__ csr_src,
                                                const float* __restrict__ dinv,
                                                const __half* __restrict__ xs2,
                                                const float* __restrict__ b2,
                                                float* __restrict__ out, int n) {
    int d = blockIdx.x * 64 + (threadIdx.x >> 2);  // 64 rows/block
    if (d >= n) return;
    int c = threadIdx.x & 3;                       // half8 slice (feats 8c..8c+7)
    const half8* __restrict__ xrow = (const half8*)xs2 + c;  // row stride 4 half8

    half8 sv = xrow[(size_t)d * 4];                // self-loop
    float a0, a1, a2, a3, a4, a5, a6, a7;
    {
        float2 f0 = __half22float2(sv.h[0]), f1 = __half22float2(sv.h[1]);
        float2 f2 = __half22float2(sv.h[2]), f3 = __half22float2(sv.h[3]);
        a0 = f0.x; a1 = f0.y; a2 = f1.x; a3 = f1.y;
        a4 = f2.x; a5 = f2.y; a6 = f3.x; a7 = f3.y;
    }

    int beg = row_ptr[d];
    int end = rend[d];
    AGG_LOOP16(4)

    float di = dinv[d];
    float4 ba = *(const float4*)&b2[8 * c];
    float4 bb = *(const float4*)&b2[8 * c + 4];
    float4 r0, r1;
    r0.x = fmaf(di, a0, ba.x);
    r0.y = fmaf(di, a1, ba.y);
    r0.z = fmaf(di, a2, ba.z);
    r0.w = fmaf(di, a3, ba.w);
    r1.x = fmaf(di, a4, bb.x);
    r1.y = fmaf(di, a5, bb.y);
    r1.z = fmaf(di, a6, bb.z);
    r1.w = fmaf(di, a7, bb.w);
    *(float4*)&out[(size_t)d * 32 + 8 * c] = r0;
    *(float4*)&out[(size_t)d * 32 + 8 * c + 4] = r1;
}

extern "C" void kernel_launch(void* const* d_in, const int* in_sizes, int n_in,
                              void* d_out, int out_size, void* d_ws, size_t ws_size,
                              hipStream_t stream) {
    const float* x  = (const float*)d_in[0];   // [n, 64]
    const int*   ei = (const int*)d_in[1];     // [2, E]
    const float* W1 = (const float*)d_in[2];   // [64, 64]
    const float* b1 = (const float*)d_in[3];   // [64]
    const float* W2 = (const float*)d_in[4];   // [64, 32]
    const float* b2 = (const float*)d_in[5];   // [32]
    float* out = (float*)d_out;                // [n, 32]

    const int n = in_sizes[0] / N_FEAT_IN;     // 100000
    const int E = in_sizes[1] / 2;             // 1600000
    const int* srcI = ei;
    const int* dstI = ei + E;

    const int NB = (n + 511) >> B2SHIFT;       // 196 coarse buckets
    const int NR = (E + CHUNK - 1) / CHUNK;    // 391 chunks

    // workspace layout (256B aligned)
    char* ws = (char*)d_ws;
    size_t off = 0;
    auto alloc = [&](size_t bytes) {
        void* p = ws + off;
        off += (bytes + 255) & ~(size_t)255;
        return p;
    };
    float*    dinv    = (float*)alloc((size_t)n * 4);
    int*      row_ptr = (int*)alloc((size_t)(n + 1) * 4);
    int*      rend    = (int*)alloc((size_t)n * 4);
    int*      gcur    = (int*)alloc((size_t)256 * 4);
    unsigned* bedges  = (unsigned*)alloc((size_t)NB * CAP * 4);     // 9.6MB
    int*      csr_src = (int*)alloc((size_t)NB * CSRCAP * 4);       // 16.1MB
    __half*   xs1     = (__half*)alloc((size_t)(n + 1) * 64 * 2);   // +pad row
    __half*   th      = (__half*)alloc((size_t)n * 64 * 2);
    __half*   xs2     = (__half*)alloc((size_t)(n + 1) * 32 * 2);   // +pad row

    // 1) build: init cursors -> place into CAP-strided buckets -> CSR (pad16)
    init_k<<<1, 256, 0, stream>>>(gcur);
    place_k<<<NR, 1024, 0, stream>>>(srcI, dstI, gcur, bedges, E);
    bucket_csr<<<NB, 1024, 0, stream>>>(gcur, bedges, row_ptr, rend, dinv, csr_src, n);

    // 2) layer 1 GEMM: xs1 = half(dinv .* (X W1))
    gemm64<<<(n + 127) / 128, 256, 0, stream>>>(x, W1, dinv, xs1, n);

    // 3) layer-1 aggregate: t = relu(dinv*(gather+self) + b1)
    agg64<<<(n + 31) / 32, 256, 0, stream>>>(row_ptr, rend, csr_src, dinv, xs1, b1, th, n);

    // 4) layer-2 transform: xs2 = half(dinv .* (t W2))
    gemm32h<<<(n + 255) / 256, 256, 0, stream>>>(th, W2, dinv, xs2, n);

    // 5) layer-2 aggregate -> out
    agg32<<<(n + 63) / 64, 256, 0, stream>>>(row_ptr, rend, csr_src, dinv, xs2, b2, out, n);
}